// Round 2
// baseline (367.327 us; speedup 1.0000x reference)
//
#include <hip/hip_runtime.h>
#include <stdint.h>

typedef __attribute__((ext_vector_type(8))) __bf16 bf16x8;
typedef __attribute__((ext_vector_type(4))) float f32x4;
typedef __attribute__((ext_vector_type(8))) unsigned short ushort8;

#define T_TOK 2048
#define D_DIM 1024
#define DFF   2816
#define NEXP  8
#define NROWS 4096   // T*K total routed pairs

#define BK    32

// ---------- helpers ----------
__device__ __forceinline__ unsigned short f2bf(float f) {
  union { float f; uint32_t u; } v; v.f = f;
  uint32_t r = (v.u + 0x7fffu + ((v.u >> 16) & 1u)) >> 16;
  return (unsigned short)r;
}

__device__ __forceinline__ void lds_cp16(const void* g, void* l) {
  __builtin_amdgcn_global_load_lds(
      (const __attribute__((address_space(1))) void*)g,
      (__attribute__((address_space(3))) void*)l, 16, 0, 0);
}

// ---------- 1. routing: deterministic per-expert compaction ----------
__global__ __launch_bounds__(512) void routing_kernel(
    const int* __restrict__ ids, const float* __restrict__ w,
    int* __restrict__ cnt, int* __restrict__ off,
    int* __restrict__ tok, float* __restrict__ wgt)
{
  __shared__ int s_cnt[NEXP];
  __shared__ int s_off[NEXP];
  const int lane = threadIdx.x & 63;
  const int e    = threadIdx.x >> 6;   // wave id == expert id (8 waves)

  int total = 0;
  for (int c = 0; c < NROWS / 64; ++c) {
    int id = ids[c * 64 + lane];
    unsigned long long b = __ballot(id == e);
    total += __popcll(b);
  }
  if (lane == 0) s_cnt[e] = total;
  __syncthreads();
  if (threadIdx.x == 0) {
    int acc = 0;
    for (int i = 0; i < NEXP; ++i) {
      s_off[i] = acc; off[i] = acc; cnt[i] = s_cnt[i]; acc += s_cnt[i];
    }
  }
  __syncthreads();
  int base = s_off[e];
  for (int c = 0; c < NROWS / 64; ++c) {
    int idx = c * 64 + lane;
    int id = ids[idx];
    bool m = (id == e);
    unsigned long long b = __ballot(m);
    int pos = __popcll(b & ((1ull << lane) - 1ull));
    if (m) { tok[base + pos] = idx >> 1; wgt[base + pos] = w[idx]; }
    base += __popcll(b);
  }
}

// ---------- 2. gather x rows into compacted bf16 matrix ----------
__global__ __launch_bounds__(256) void gather_x_kernel(
    const float* __restrict__ x, const int* __restrict__ tok,
    unsigned short* __restrict__ xg)
{
  const int i = blockIdx.x;
  const int t = tok[i];
  const float4 v = ((const float4*)(x + (size_t)t * D_DIM))[threadIdx.x];
  ushort4 o;
  o.x = f2bf(v.x); o.y = f2bf(v.y); o.z = f2bf(v.z); o.w = f2bf(v.w);
  ((ushort4*)(xg + (size_t)i * D_DIM))[threadIdx.x] = o;
}

// ---------- 3. grouped GEMM: h = silu(x gateT) * (x upT) * w_route ----------
#define BM_A 128
#define BN_A 64
#define NT_A (DFF / BN_A)       // 44
#define MAXMT_A (NROWS / BM_A)  // 32

__global__ __launch_bounds__(256) void moe_gateup(
    const float* __restrict__ gate_w, const float* __restrict__ up_w,
    const unsigned short* __restrict__ xg, const float* __restrict__ wgt,
    const int* __restrict__ cnt, const int* __restrict__ off,
    unsigned short* __restrict__ hbuf)
{
  const int e = blockIdx.z;
  const int cnte = cnt[e];
  const int m0 = blockIdx.y * BM_A;
  if (m0 >= cnte) return;
  const int row_base = off[e] + m0;
  const int valid = min(BM_A, cnte - m0);
  const int n0 = blockIdx.x * BN_A;

  __shared__ __align__(16) unsigned short Alds[BM_A * BK]; // 8KB
  __shared__ __align__(16) unsigned short Bg[BN_A * BK];   // 4KB
  __shared__ __align__(16) unsigned short Bu[BN_A * BK];   // 4KB

  const int tid = threadIdx.x;
  const int lane = tid & 63;
  const int wid = tid >> 6;
  const int wm = wid >> 1, wn = wid & 1;   // wave subtile 64x32
  const int lhi = lane >> 4, llo = lane & 15;

  f32x4 accg[4][2], accu[4][2];
  #pragma unroll
  for (int i = 0; i < 4; ++i)
    #pragma unroll
    for (int j = 0; j < 2; ++j) {
      accg[i][j] = (f32x4){0.f, 0.f, 0.f, 0.f};
      accu[i][j] = (f32x4){0.f, 0.f, 0.f, 0.f};
    }

  const float* gbase = gate_w + ((size_t)e * DFF + n0) * D_DIM;
  const float* ubase = up_w   + ((size_t)e * DFF + n0) * D_DIM;
  const int rowb = tid >> 2;
  const int colb = (tid & 3) * 8;

  for (int k0 = 0; k0 < D_DIM; k0 += BK) {
    __syncthreads();
    // A tile: 128x32 bf16 via global_load_lds (2 x 16B per thread)
    #pragma unroll
    for (int j = 0; j < 2; ++j) {
      int flat = j * 2048 + tid * 8;          // element index
      int row = flat >> 5, col = flat & 31;
      int r = min(row, valid - 1);
      lds_cp16(xg + (size_t)(row_base + r) * D_DIM + k0 + col, &Alds[flat]);
    }
    // B tiles: 64x32 f32 each -> bf16 in LDS
    {
      const float* gp = gbase + (size_t)rowb * D_DIM + k0 + colb;
      const float* up = ubase + (size_t)rowb * D_DIM + k0 + colb;
      float4 g0 = *(const float4*)gp;  float4 g1 = *(const float4*)(gp + 4);
      float4 u0 = *(const float4*)up;  float4 u1 = *(const float4*)(up + 4);
      ushort8 pg, pu;
      pg[0]=f2bf(g0.x); pg[1]=f2bf(g0.y); pg[2]=f2bf(g0.z); pg[3]=f2bf(g0.w);
      pg[4]=f2bf(g1.x); pg[5]=f2bf(g1.y); pg[6]=f2bf(g1.z); pg[7]=f2bf(g1.w);
      pu[0]=f2bf(u0.x); pu[1]=f2bf(u0.y); pu[2]=f2bf(u0.z); pu[3]=f2bf(u0.w);
      pu[4]=f2bf(u1.x); pu[5]=f2bf(u1.y); pu[6]=f2bf(u1.z); pu[7]=f2bf(u1.w);
      *(ushort8*)&Bg[rowb * BK + colb] = pg;
      *(ushort8*)&Bu[rowb * BK + colb] = pu;
    }
    __syncthreads();

    bf16x8 a[4], bgf[2], buf[2];
    #pragma unroll
    for (int mi = 0; mi < 4; ++mi)
      a[mi] = *(const bf16x8*)&Alds[(wm * 64 + mi * 16 + llo) * BK + lhi * 8];
    #pragma unroll
    for (int ni = 0; ni < 2; ++ni) {
      bgf[ni] = *(const bf16x8*)&Bg[(wn * 32 + ni * 16 + llo) * BK + lhi * 8];
      buf[ni] = *(const bf16x8*)&Bu[(wn * 32 + ni * 16 + llo) * BK + lhi * 8];
    }
    #pragma unroll
    for (int mi = 0; mi < 4; ++mi)
      #pragma unroll
      for (int ni = 0; ni < 2; ++ni) {
        accg[mi][ni] = __builtin_amdgcn_mfma_f32_16x16x32_bf16(a[mi], bgf[ni], accg[mi][ni], 0, 0, 0);
        accu[mi][ni] = __builtin_amdgcn_mfma_f32_16x16x32_bf16(a[mi], buf[ni], accu[mi][ni], 0, 0, 0);
      }
  }

  // epilogue: h = silu(g)*u*w -> bf16
  #pragma unroll
  for (int mi = 0; mi < 4; ++mi) {
    #pragma unroll
    for (int r = 0; r < 4; ++r) {
      int row = wm * 64 + mi * 16 + lhi * 4 + r;
      if (row < valid) {
        int grow = row_base + row;
        float wv = wgt[grow];
        size_t base = (size_t)grow * DFF + n0 + wn * 32;
        #pragma unroll
        for (int ni = 0; ni < 2; ++ni) {
          float g = accg[mi][ni][r];
          float u = accu[mi][ni][r];
          float h = (g / (1.f + __expf(-g))) * u * wv;
          hbuf[base + ni * 16 + llo] = f2bf(h);
        }
      }
    }
  }
}

// ---------- 4. grouped GEMM: out[t] += h downT ----------
#define BM_B 64
#define BN_B 128
#define NT_B (D_DIM / BN_B)     // 8
#define MAXMT_B (NROWS / BM_B)  // 64

__global__ __launch_bounds__(256) void moe_down(
    const float* __restrict__ down_w,
    const unsigned short* __restrict__ hbuf,
    const int* __restrict__ tok,
    const int* __restrict__ cnt, const int* __restrict__ off,
    float* __restrict__ out)
{
  const int e = blockIdx.z;
  const int cnte = cnt[e];
  const int m0 = blockIdx.y * BM_B;
  if (m0 >= cnte) return;
  const int row_base = off[e] + m0;
  const int valid = min(BM_B, cnte - m0);
  const int n0 = blockIdx.x * BN_B;

  __shared__ __align__(16) unsigned short Alds[BM_B * BK]; // 4KB
  __shared__ __align__(16) unsigned short Blds[BN_B * BK]; // 8KB

  const int tid = threadIdx.x, lane = tid & 63, wid = tid >> 6;
  const int wm = wid >> 1, wn = wid & 1;   // wave subtile 32x64
  const int lhi = lane >> 4, llo = lane & 15;

  f32x4 acc[2][4];
  #pragma unroll
  for (int i = 0; i < 2; ++i)
    #pragma unroll
    for (int j = 0; j < 4; ++j) acc[i][j] = (f32x4){0.f, 0.f, 0.f, 0.f};

  const float* dbase = down_w + ((size_t)e * D_DIM + n0) * DFF;
  const int rowb = tid >> 1;
  const int colb = (tid & 1) * 16;

  for (int k0 = 0; k0 < DFF; k0 += BK) {
    __syncthreads();
    // A tile: 64x32 bf16 (one 16B chunk per thread)
    {
      int flat = tid * 8;
      int row = flat >> 5, col = flat & 31;
      int r = min(row, valid - 1);
      lds_cp16(hbuf + (size_t)(row_base + r) * DFF + k0 + col, &Alds[flat]);
    }
    // B tile: 128x32 f32 -> bf16
    {
      const float* dp = dbase + (size_t)rowb * DFF + k0 + colb;
      float4 d0 = *(const float4*)dp;       float4 d1 = *(const float4*)(dp + 4);
      float4 d2 = *(const float4*)(dp + 8); float4 d3 = *(const float4*)(dp + 12);
      ushort8 p0, p1;
      p0[0]=f2bf(d0.x); p0[1]=f2bf(d0.y); p0[2]=f2bf(d0.z); p0[3]=f2bf(d0.w);
      p0[4]=f2bf(d1.x); p0[5]=f2bf(d1.y); p0[6]=f2bf(d1.z); p0[7]=f2bf(d1.w);
      p1[0]=f2bf(d2.x); p1[1]=f2bf(d2.y); p1[2]=f2bf(d2.z); p1[3]=f2bf(d2.w);
      p1[4]=f2bf(d3.x); p1[5]=f2bf(d3.y); p1[6]=f2bf(d3.z); p1[7]=f2bf(d3.w);
      *(ushort8*)&Blds[rowb * BK + colb] = p0;
      *(ushort8*)&Blds[rowb * BK + colb + 8] = p1;
    }
    __syncthreads();

    bf16x8 a[2], b[4];
    #pragma unroll
    for (int mi = 0; mi < 2; ++mi)
      a[mi] = *(const bf16x8*)&Alds[(wm * 32 + mi * 16 + llo) * BK + lhi * 8];
    #pragma unroll
    for (int ni = 0; ni < 4; ++ni)
      b[ni] = *(const bf16x8*)&Blds[(wn * 64 + ni * 16 + llo) * BK + lhi * 8];
    #pragma unroll
    for (int mi = 0; mi < 2; ++mi)
      #pragma unroll
      for (int ni = 0; ni < 4; ++ni)
        acc[mi][ni] = __builtin_amdgcn_mfma_f32_16x16x32_bf16(a[mi], b[ni], acc[mi][ni], 0, 0, 0);
  }

  #pragma unroll
  for (int mi = 0; mi < 2; ++mi) {
    #pragma unroll
    for (int r = 0; r < 4; ++r) {
      int row = wm * 32 + mi * 16 + lhi * 4 + r;
      if (row < valid) {
        int t = tok[row_base + row];
        float* op = out + (size_t)t * D_DIM + n0 + wn * 64;
        #pragma unroll
        for (int ni = 0; ni < 4; ++ni)
          atomicAdd(op + ni * 16 + llo, acc[mi][ni][r]);
      }
    }
  }
}

// ---------- launch ----------
extern "C" void kernel_launch(void* const* d_in, const int* in_sizes, int n_in,
                              void* d_out, int out_size, void* d_ws, size_t ws_size,
                              hipStream_t stream) {
  const float* x      = (const float*)d_in[0];
  const float* topk_w = (const float*)d_in[1];
  const float* gate_w = (const float*)d_in[2];
  const float* up_w   = (const float*)d_in[3];
  const float* down_w = (const float*)d_in[4];
  const int*   ids    = (const int*)d_in[5];
  float* out = (float*)d_out;

  char* ws = (char*)d_ws;
  int*   cnt = (int*)(ws + 0);
  int*   off = (int*)(ws + 32);
  int*   tok = (int*)(ws + 64);
  float* wgt = (float*)(ws + 64 + NROWS * 4);
  unsigned short* xg   = (unsigned short*)(ws + 36864);
  unsigned short* hbuf = (unsigned short*)(ws + 36864 + (size_t)NROWS * D_DIM * 2);

  hipMemsetAsync(d_out, 0, (size_t)out_size * sizeof(float), stream);
  routing_kernel<<<1, 512, 0, stream>>>(ids, topk_w, cnt, off, tok, wgt);
  gather_x_kernel<<<NROWS, 256, 0, stream>>>(x, tok, xg);
  moe_gateup<<<dim3(NT_A, MAXMT_A, NEXP), 256, 0, stream>>>(gate_w, up_w, xg, wgt, cnt, off, hbuf);
  moe_down<<<dim3(NT_B, MAXMT_B, NEXP), 256, 0, stream>>>(down_w, hbuf, tok, cnt, off, out);
}

// Round 3
// 342.160 us; speedup vs baseline: 1.0736x; 1.0736x over previous
//
#include <hip/hip_runtime.h>
#include <stdint.h>

typedef __attribute__((ext_vector_type(8))) __bf16 bf16x8;
typedef __attribute__((ext_vector_type(4))) float f32x4;
typedef __attribute__((ext_vector_type(8))) unsigned short ushort8;

#define T_TOK 2048
#define D_DIM 1024
#define DFF   2816
#define NEXP  8
#define NROWS 4096   // T*K total routed pairs
#define BK    32
#define SPLITK 2
#define KSLICE (DFF / SPLITK)   // 1408

// granule swizzle: 16B granule g of row r -> g ^ ((r>>1)&3); involution.
#define SWZ(r,g) ((g) ^ (((r) >> 1) & 3))

// ---------- helpers ----------
__device__ __forceinline__ unsigned short f2bf(float f) {
  union { float f; uint32_t u; } v; v.f = f;
  uint32_t r = (v.u + 0x7fffu + ((v.u >> 16) & 1u)) >> 16;
  return (unsigned short)r;
}

__device__ __forceinline__ void lds_cp16(const void* g, void* l) {
  __builtin_amdgcn_global_load_lds(
      (const __attribute__((address_space(1))) void*)g,
      (__attribute__((address_space(3))) void*)l, 16, 0, 0);
}

// ---------- 1. routing: deterministic per-expert compaction ----------
__global__ __launch_bounds__(512) void routing_kernel(
    const int* __restrict__ ids, const float* __restrict__ w,
    int* __restrict__ cnt, int* __restrict__ off,
    int* __restrict__ tok, float* __restrict__ wgt, int* __restrict__ rowmap)
{
  __shared__ int s_cnt[NEXP];
  __shared__ int s_off[NEXP];
  const int lane = threadIdx.x & 63;
  const int e    = threadIdx.x >> 6;   // wave id == expert id (8 waves)

  int total = 0;
  for (int c = 0; c < NROWS / 64; ++c) {
    int id = ids[c * 64 + lane];
    unsigned long long b = __ballot(id == e);
    total += __popcll(b);
  }
  if (lane == 0) s_cnt[e] = total;
  __syncthreads();
  if (threadIdx.x == 0) {
    int acc = 0;
    for (int i = 0; i < NEXP; ++i) {
      s_off[i] = acc; off[i] = acc; cnt[i] = s_cnt[i]; acc += s_cnt[i];
    }
  }
  __syncthreads();
  int base = s_off[e];
  for (int c = 0; c < NROWS / 64; ++c) {
    int idx = c * 64 + lane;
    int id = ids[idx];
    bool m = (id == e);
    unsigned long long b = __ballot(m);
    int pos = __popcll(b & ((1ull << lane) - 1ull));
    if (m) {
      tok[base + pos] = idx >> 1;
      wgt[base + pos] = w[idx];
      rowmap[idx] = base + pos;
    }
    base += __popcll(b);
  }
}

// ---------- 2. gather x rows into compacted bf16 matrix ----------
__global__ __launch_bounds__(256) void gather_x_kernel(
    const float* __restrict__ x, const int* __restrict__ tok,
    unsigned short* __restrict__ xg)
{
  const int i = blockIdx.x;
  const int t = tok[i];
  const float4 v = ((const float4*)(x + (size_t)t * D_DIM))[threadIdx.x];
  ushort4 o;
  o.x = f2bf(v.x); o.y = f2bf(v.y); o.z = f2bf(v.z); o.w = f2bf(v.w);
  ((ushort4*)(xg + (size_t)i * D_DIM))[threadIdx.x] = o;
}

// ---------- 3. grouped GEMM: h = silu(x gateT) * (x upT) * w_route ----------
#define BM_A 128
#define BN_A 64
#define NT_A (DFF / BN_A)       // 44
#define MT_A (NROWS / BM_A)     // 32
#define NWG_A (NT_A * MT_A * NEXP)  // 11264

__global__ __launch_bounds__(256) void moe_gateup(
    const float* __restrict__ gate_w, const float* __restrict__ up_w,
    const unsigned short* __restrict__ xg, const float* __restrict__ wgt,
    const int* __restrict__ cnt, const int* __restrict__ off,
    unsigned short* __restrict__ hbuf)
{
  // XCD-aware bijective chunked remap (NWG_A % 8 == 0), m-tile fastest.
  const int orig = blockIdx.x;
  const int wgid = (orig & 7) * (NWG_A >> 3) + (orig >> 3);
  const int mt = wgid % MT_A;
  const int t1 = wgid / MT_A;
  const int nt = t1 % NT_A;
  const int e  = t1 / NT_A;

  const int cnte = cnt[e];
  const int m0 = mt * BM_A;
  if (m0 >= cnte) return;
  const int row_base = off[e] + m0;
  const int valid = min(BM_A, cnte - m0);
  const int n0 = nt * BN_A;

  __shared__ __align__(16) unsigned short Alds[BM_A * BK]; // 8KB
  __shared__ __align__(16) unsigned short Bg[BN_A * BK];   // 4KB
  __shared__ __align__(16) unsigned short Bu[BN_A * BK];   // 4KB

  const int tid = threadIdx.x;
  const int lane = tid & 63;
  const int wid = tid >> 6;
  const int wm = wid >> 1, wn = wid & 1;   // wave subtile 64x32
  const int lhi = lane >> 4, llo = lane & 15;

  f32x4 accg[4][2], accu[4][2];
  #pragma unroll
  for (int i = 0; i < 4; ++i)
    #pragma unroll
    for (int j = 0; j < 2; ++j) {
      accg[i][j] = (f32x4){0.f, 0.f, 0.f, 0.f};
      accu[i][j] = (f32x4){0.f, 0.f, 0.f, 0.f};
    }

  const float* gbase = gate_w + ((size_t)e * DFF + n0) * D_DIM;
  const float* ubase = up_w   + ((size_t)e * DFF + n0) * D_DIM;
  const int rowb = tid >> 2;         // B stage row (0..63)
  const int gidx = tid & 3;          // B stage granule

  // A staging rows/granules for the two lds_cp16 per thread
  const int ar0 = tid >> 2,          ag0 = tid & 3;
  const int ar1 = (tid + 256) >> 2,  ag1 = tid & 3;
  const int arow0 = row_base + min(ar0, valid - 1);
  const int arow1 = row_base + min(ar1, valid - 1);

  for (int k0 = 0; k0 < D_DIM; k0 += BK) {
    __syncthreads();
    // A tile: 128x32 bf16 via global_load_lds, source pre-swizzled
    lds_cp16(xg + (size_t)arow0 * D_DIM + k0 + SWZ(ar0, ag0) * 8, &Alds[tid * 8]);
    lds_cp16(xg + (size_t)arow1 * D_DIM + k0 + SWZ(ar1, ag1) * 8, &Alds[(tid + 256) * 8]);
    // B tiles: 64x32 f32 each -> bf16 in LDS (swizzled write)
    {
      const float* gp = gbase + (size_t)rowb * D_DIM + k0 + gidx * 8;
      const float* up = ubase + (size_t)rowb * D_DIM + k0 + gidx * 8;
      float4 g0 = *(const float4*)gp;  float4 g1 = *(const float4*)(gp + 4);
      float4 u0 = *(const float4*)up;  float4 u1 = *(const float4*)(up + 4);
      ushort8 pg, pu;
      pg[0]=f2bf(g0.x); pg[1]=f2bf(g0.y); pg[2]=f2bf(g0.z); pg[3]=f2bf(g0.w);
      pg[4]=f2bf(g1.x); pg[5]=f2bf(g1.y); pg[6]=f2bf(g1.z); pg[7]=f2bf(g1.w);
      pu[0]=f2bf(u0.x); pu[1]=f2bf(u0.y); pu[2]=f2bf(u0.z); pu[3]=f2bf(u0.w);
      pu[4]=f2bf(u1.x); pu[5]=f2bf(u1.y); pu[6]=f2bf(u1.z); pu[7]=f2bf(u1.w);
      *(ushort8*)&Bg[rowb * BK + SWZ(rowb, gidx) * 8] = pg;
      *(ushort8*)&Bu[rowb * BK + SWZ(rowb, gidx) * 8] = pu;
    }
    __syncthreads();

    bf16x8 a[4], bgf[2], buf[2];
    #pragma unroll
    for (int mi = 0; mi < 4; ++mi) {
      int row = wm * 64 + mi * 16 + llo;
      a[mi] = *(const bf16x8*)&Alds[row * BK + SWZ(row, lhi) * 8];
    }
    #pragma unroll
    for (int ni = 0; ni < 2; ++ni) {
      int row = wn * 32 + ni * 16 + llo;
      bgf[ni] = *(const bf16x8*)&Bg[row * BK + SWZ(row, lhi) * 8];
      buf[ni] = *(const bf16x8*)&Bu[row * BK + SWZ(row, lhi) * 8];
    }
    #pragma unroll
    for (int mi = 0; mi < 4; ++mi)
      #pragma unroll
      for (int ni = 0; ni < 2; ++ni) {
        accg[mi][ni] = __builtin_amdgcn_mfma_f32_16x16x32_bf16(a[mi], bgf[ni], accg[mi][ni], 0, 0, 0);
        accu[mi][ni] = __builtin_amdgcn_mfma_f32_16x16x32_bf16(a[mi], buf[ni], accu[mi][ni], 0, 0, 0);
      }
  }

  // epilogue: h = silu(g)*u*w -> bf16
  #pragma unroll
  for (int mi = 0; mi < 4; ++mi) {
    #pragma unroll
    for (int r = 0; r < 4; ++r) {
      int row = wm * 64 + mi * 16 + lhi * 4 + r;
      if (row < valid) {
        int grow = row_base + row;
        float wv = wgt[grow];
        size_t base = (size_t)grow * DFF + n0 + wn * 32;
        #pragma unroll
        for (int ni = 0; ni < 2; ++ni) {
          float g = accg[mi][ni][r];
          float u = accu[mi][ni][r];
          float h = (g / (1.f + __expf(-g))) * u * wv;
          hbuf[base + ni * 16 + llo] = f2bf(h);
        }
      }
    }
  }
}

// ---------- 4. grouped GEMM (split-K): y = h downT ----------
#define BM_B 64
#define BN_B 128
#define NT_B (D_DIM / BN_B)     // 8
#define MT_B (NROWS / BM_B)     // 64
#define NWG_B (NT_B * MT_B * NEXP * SPLITK)  // 8192

template <bool USE_YBUF>
__global__ __launch_bounds__(256) void moe_down(
    const float* __restrict__ down_w,
    const unsigned short* __restrict__ hbuf,
    const int* __restrict__ tok,
    const int* __restrict__ cnt, const int* __restrict__ off,
    float* __restrict__ ybuf_or_out)
{
  const int orig = blockIdx.x;
  const int wgid = (orig & 7) * (NWG_B >> 3) + (orig >> 3);
  const int mt = wgid % MT_B;
  const int t1 = wgid / MT_B;
  const int nt = t1 % NT_B;
  const int t2 = t1 / NT_B;
  const int e  = t2 % NEXP;
  const int sl = t2 / NEXP;           // k-slice

  const int cnte = cnt[e];
  const int m0 = mt * BM_B;
  if (m0 >= cnte) return;
  const int row_base = off[e] + m0;
  const int valid = min(BM_B, cnte - m0);
  const int n0 = nt * BN_B;
  const int kbeg = sl * KSLICE, kend = kbeg + KSLICE;

  __shared__ __align__(16) unsigned short Alds[BM_B * BK]; // 4KB
  __shared__ __align__(16) unsigned short Blds[BN_B * BK]; // 8KB

  const int tid = threadIdx.x, lane = tid & 63, wid = tid >> 6;
  const int wm = wid >> 1, wn = wid & 1;   // wave subtile 32x64
  const int lhi = lane >> 4, llo = lane & 15;

  f32x4 acc[2][4];
  #pragma unroll
  for (int i = 0; i < 2; ++i)
    #pragma unroll
    for (int j = 0; j < 4; ++j) acc[i][j] = (f32x4){0.f, 0.f, 0.f, 0.f};

  const float* dbase = down_w + ((size_t)e * D_DIM + n0) * DFF;
  const int ar = tid >> 2, ag = tid & 3;               // A stage granule
  const int arow = row_base + min(ar, valid - 1);
  const int browb = tid >> 1;                          // B stage row 0..127
  const int bg0 = (tid & 1) * 2;                       // B granules bg0, bg0+1

  for (int k0 = kbeg; k0 < kend; k0 += BK) {
    __syncthreads();
    // A tile: 64x32 bf16, source pre-swizzled
    lds_cp16(hbuf + (size_t)arow * DFF + k0 + SWZ(ar, ag) * 8, &Alds[tid * 8]);
    // B tile: 128x32 f32 -> bf16 (swizzled write)
    {
      const float* dp = dbase + (size_t)browb * DFF + k0 + bg0 * 8;
      float4 d0 = *(const float4*)dp;       float4 d1 = *(const float4*)(dp + 4);
      float4 d2 = *(const float4*)(dp + 8); float4 d3 = *(const float4*)(dp + 12);
      ushort8 p0, p1;
      p0[0]=f2bf(d0.x); p0[1]=f2bf(d0.y); p0[2]=f2bf(d0.z); p0[3]=f2bf(d0.w);
      p0[4]=f2bf(d1.x); p0[5]=f2bf(d1.y); p0[6]=f2bf(d1.z); p0[7]=f2bf(d1.w);
      p1[0]=f2bf(d2.x); p1[1]=f2bf(d2.y); p1[2]=f2bf(d2.z); p1[3]=f2bf(d2.w);
      p1[4]=f2bf(d3.x); p1[5]=f2bf(d3.y); p1[6]=f2bf(d3.z); p1[7]=f2bf(d3.w);
      *(ushort8*)&Blds[browb * BK + SWZ(browb, bg0) * 8]     = p0;
      *(ushort8*)&Blds[browb * BK + SWZ(browb, bg0 + 1) * 8] = p1;
    }
    __syncthreads();

    bf16x8 a[2], b[4];
    #pragma unroll
    for (int mi = 0; mi < 2; ++mi) {
      int row = wm * 32 + mi * 16 + llo;
      a[mi] = *(const bf16x8*)&Alds[row * BK + SWZ(row, lhi) * 8];
    }
    #pragma unroll
    for (int ni = 0; ni < 4; ++ni) {
      int row = wn * 64 + ni * 16 + llo;
      b[ni] = *(const bf16x8*)&Blds[row * BK + SWZ(row, lhi) * 8];
    }
    #pragma unroll
    for (int mi = 0; mi < 2; ++mi)
      #pragma unroll
      for (int ni = 0; ni < 4; ++ni)
        acc[mi][ni] = __builtin_amdgcn_mfma_f32_16x16x32_bf16(a[mi], b[ni], acc[mi][ni], 0, 0, 0);
  }

  #pragma unroll
  for (int mi = 0; mi < 2; ++mi) {
    #pragma unroll
    for (int r = 0; r < 4; ++r) {
      int row = wm * 32 + mi * 16 + lhi * 4 + r;
      if (row < valid) {
        if (USE_YBUF) {
          float* yp = ybuf_or_out + ((size_t)sl * NROWS + row_base + row) * D_DIM + n0 + wn * 64;
          #pragma unroll
          for (int ni = 0; ni < 4; ++ni) yp[ni * 16 + llo] = acc[mi][ni][r];
        } else {
          int t = tok[row_base + row];
          float* op = ybuf_or_out + (size_t)t * D_DIM + n0 + wn * 64;
          #pragma unroll
          for (int ni = 0; ni < 4; ++ni) atomicAdd(op + ni * 16 + llo, acc[mi][ni][r]);
        }
      }
    }
  }
}

// ---------- 5. combine: out[t] = sum over K slots and k-slices ----------
__global__ __launch_bounds__(256) void combine_kernel(
    const float* __restrict__ ybuf, const int* __restrict__ rowmap,
    float* __restrict__ out)
{
  const int t = blockIdx.x;
  const int d = threadIdx.x * 4;
  const int r0 = rowmap[t * 2], r1 = rowmap[t * 2 + 1];
  const float4 a0 = *(const float4*)(ybuf + ((size_t)r0) * D_DIM + d);
  const float4 a1 = *(const float4*)(ybuf + ((size_t)NROWS + r0) * D_DIM + d);
  const float4 b0 = *(const float4*)(ybuf + ((size_t)r1) * D_DIM + d);
  const float4 b1 = *(const float4*)(ybuf + ((size_t)NROWS + r1) * D_DIM + d);
  float4 s;
  s.x = (a0.x + a1.x) + (b0.x + b1.x);
  s.y = (a0.y + a1.y) + (b0.y + b1.y);
  s.z = (a0.z + a1.z) + (b0.z + b1.z);
  s.w = (a0.w + a1.w) + (b0.w + b1.w);
  *(float4*)(out + (size_t)t * D_DIM + d) = s;
}

// ---------- launch ----------
extern "C" void kernel_launch(void* const* d_in, const int* in_sizes, int n_in,
                              void* d_out, int out_size, void* d_ws, size_t ws_size,
                              hipStream_t stream) {
  const float* x      = (const float*)d_in[0];
  const float* topk_w = (const float*)d_in[1];
  const float* gate_w = (const float*)d_in[2];
  const float* up_w   = (const float*)d_in[3];
  const float* down_w = (const float*)d_in[4];
  const int*   ids    = (const int*)d_in[5];
  float* out = (float*)d_out;

  char* ws = (char*)d_ws;
  int*   cnt    = (int*)(ws + 0);
  int*   off    = (int*)(ws + 32);
  int*   tok    = (int*)(ws + 64);
  float* wgt    = (float*)(ws + 64 + NROWS * 4);
  int*   rowmap = (int*)(ws + 64 + NROWS * 8);
  unsigned short* xg   = (unsigned short*)(ws + 65536);
  unsigned short* hbuf = (unsigned short*)(ws + 65536 + (size_t)NROWS * D_DIM * 2);
  float* ybuf = (float*)(ws + 65536 + (size_t)NROWS * D_DIM * 2 + (size_t)NROWS * DFF * 2);
  const size_t needed = 65536 + (size_t)NROWS * D_DIM * 2 + (size_t)NROWS * DFF * 2
                      + (size_t)SPLITK * NROWS * D_DIM * 4;
  const bool use_ybuf = ws_size >= needed;

  routing_kernel<<<1, 512, 0, stream>>>(ids, topk_w, cnt, off, tok, wgt, rowmap);
  gather_x_kernel<<<NROWS, 256, 0, stream>>>(x, tok, xg);
  moe_gateup<<<NWG_A, 256, 0, stream>>>(gate_w, up_w, xg, wgt, cnt, off, hbuf);
  if (use_ybuf) {
    moe_down<true><<<NWG_B, 256, 0, stream>>>(down_w, hbuf, tok, cnt, off, ybuf);
    combine_kernel<<<T_TOK, 256, 0, stream>>>(ybuf, rowmap, out);
  } else {
    hipMemsetAsync(d_out, 0, (size_t)out_size * sizeof(float), stream);
    moe_down<false><<<NWG_B, 256, 0, stream>>>(down_w, hbuf, tok, cnt, off, out);
  }
}

// Round 4
// 326.808 us; speedup vs baseline: 1.1240x; 1.0470x over previous
//
#include <hip/hip_runtime.h>
#include <stdint.h>

typedef __attribute__((ext_vector_type(8))) __bf16 bf16x8;
typedef __attribute__((ext_vector_type(4))) float f32x4;
typedef __attribute__((ext_vector_type(8))) unsigned short ushort8;

#define T_TOK 2048
#define D_DIM 1024
#define DFF   2816
#define NEXP  8
#define NROWS 4096   // T*K total routed pairs
#define BK    32
#define SPLITK 2
#define KSLICE (DFF / SPLITK)   // 1408

// granule swizzle: 16B granule g of row r -> g ^ ((r>>1)&3); involution.
#define SWZ(r,g) ((g) ^ (((r) >> 1) & 3))

// ---------- helpers ----------
__device__ __forceinline__ unsigned short f2bf(float f) {
  union { float f; uint32_t u; } v; v.f = f;
  uint32_t r = (v.u + 0x7fffu + ((v.u >> 16) & 1u)) >> 16;
  return (unsigned short)r;
}

__device__ __forceinline__ void lds_cp16(const void* g, void* l) {
  __builtin_amdgcn_global_load_lds(
      (const __attribute__((address_space(1))) void*)g,
      (__attribute__((address_space(3))) void*)l, 16, 0, 0);
}

__device__ __forceinline__ ushort8 pack_bf16x8(float4 a, float4 b) {
  ushort8 p;
  p[0]=f2bf(a.x); p[1]=f2bf(a.y); p[2]=f2bf(a.z); p[3]=f2bf(a.w);
  p[4]=f2bf(b.x); p[5]=f2bf(b.y); p[6]=f2bf(b.z); p[7]=f2bf(b.w);
  return p;
}

// ---------- 1. routing: deterministic per-expert compaction ----------
__global__ __launch_bounds__(512) void routing_kernel(
    const int* __restrict__ ids, const float* __restrict__ w,
    int* __restrict__ cnt, int* __restrict__ off,
    int* __restrict__ tok, float* __restrict__ wgt, int* __restrict__ rowmap)
{
  __shared__ int s_cnt[NEXP];
  __shared__ int s_off[NEXP];
  const int lane = threadIdx.x & 63;
  const int e    = threadIdx.x >> 6;   // wave id == expert id (8 waves)

  int total = 0;
  for (int c = 0; c < NROWS / 64; ++c) {
    int id = ids[c * 64 + lane];
    unsigned long long b = __ballot(id == e);
    total += __popcll(b);
  }
  if (lane == 0) s_cnt[e] = total;
  __syncthreads();
  if (threadIdx.x == 0) {
    int acc = 0;
    for (int i = 0; i < NEXP; ++i) {
      s_off[i] = acc; off[i] = acc; cnt[i] = s_cnt[i]; acc += s_cnt[i];
    }
  }
  __syncthreads();
  int base = s_off[e];
  for (int c = 0; c < NROWS / 64; ++c) {
    int idx = c * 64 + lane;
    int id = ids[idx];
    bool m = (id == e);
    unsigned long long b = __ballot(m);
    int pos = __popcll(b & ((1ull << lane) - 1ull));
    if (m) {
      tok[base + pos] = idx >> 1;
      wgt[base + pos] = w[idx];
      rowmap[idx] = base + pos;
    }
    base += __popcll(b);
  }
}

// ---------- 2. gather x rows into compacted bf16 matrix ----------
__global__ __launch_bounds__(256) void gather_x_kernel(
    const float* __restrict__ x, const int* __restrict__ tok,
    unsigned short* __restrict__ xg)
{
  const int i = blockIdx.x;
  const int t = tok[i];
  const float4 v = ((const float4*)(x + (size_t)t * D_DIM))[threadIdx.x];
  ushort4 o;
  o.x = f2bf(v.x); o.y = f2bf(v.y); o.z = f2bf(v.z); o.w = f2bf(v.w);
  ((ushort4*)(xg + (size_t)i * D_DIM))[threadIdx.x] = o;
}

// ---------- 3. grouped GEMM (2-phase pipelined): h = silu(x gT)*(x uT)*w ----------
#define BM_A 128
#define BN_A 64
#define NT_A (DFF / BN_A)       // 44
#define MT_A (NROWS / BM_A)     // 32
#define NWG_A (NT_A * MT_A * NEXP)  // 11264
#define KT_A (D_DIM / BK)       // 32

__global__ __launch_bounds__(256) void moe_gateup(
    const float* __restrict__ gate_w, const float* __restrict__ up_w,
    const unsigned short* __restrict__ xg, const float* __restrict__ wgt,
    const int* __restrict__ cnt, const int* __restrict__ off,
    unsigned short* __restrict__ hbuf)
{
  const int orig = blockIdx.x;
  const int wgid = (orig & 7) * (NWG_A >> 3) + (orig >> 3);
  const int mt = wgid % MT_A;
  const int t1 = wgid / MT_A;
  const int nt = t1 % NT_A;
  const int e  = t1 / NT_A;

  const int cnte = cnt[e];
  const int m0 = mt * BM_A;
  if (m0 >= cnte) return;
  const int row_base = off[e] + m0;
  const int valid = min(BM_A, cnte - m0);
  const int n0 = nt * BN_A;

  __shared__ __align__(16) unsigned short Alds[2][BM_A * BK]; // 2 x 8KB
  __shared__ __align__(16) unsigned short Bg[2][BN_A * BK];   // 2 x 4KB
  __shared__ __align__(16) unsigned short Bu[2][BN_A * BK];   // 2 x 4KB

  const int tid = threadIdx.x;
  const int lane = tid & 63;
  const int wid = tid >> 6;
  const int wm = wid >> 1, wn = wid & 1;   // wave subtile 64x32
  const int lhi = lane >> 4, llo = lane & 15;

  f32x4 accg[4][2], accu[4][2];
  #pragma unroll
  for (int i = 0; i < 4; ++i)
    #pragma unroll
    for (int j = 0; j < 2; ++j) {
      accg[i][j] = (f32x4){0.f, 0.f, 0.f, 0.f};
      accu[i][j] = (f32x4){0.f, 0.f, 0.f, 0.f};
    }

  const float* gbase = gate_w + ((size_t)e * DFF + n0) * D_DIM;
  const float* ubase = up_w   + ((size_t)e * DFF + n0) * D_DIM;
  const int rowb = tid >> 2;         // B stage row (0..63)
  const int gidx = tid & 3;          // B stage granule

  const int ar0 = tid >> 2,          ag0 = tid & 3;
  const int ar1 = (tid + 256) >> 2,  ag1 = tid & 3;
  const size_t arow0 = (size_t)(row_base + min(ar0, valid - 1)) * D_DIM + SWZ(ar0, ag0) * 8;
  const size_t arow1 = (size_t)(row_base + min(ar1, valid - 1)) * D_DIM + SWZ(ar1, ag1) * 8;
  const size_t boff  = (size_t)rowb * D_DIM + gidx * 8;
  const int bws = rowb * BK + SWZ(rowb, gidx) * 8;  // swizzled B LDS elem offset

  // prologue: stage k=0 into buffer 0
  lds_cp16(xg + arow0, &Alds[0][tid * 8]);
  lds_cp16(xg + arow1, &Alds[0][(tid + 256) * 8]);
  {
    const float* gp = gbase + boff;
    const float* up = ubase + boff;
    *(ushort8*)&Bg[0][bws] = pack_bf16x8(*(const float4*)gp, *(const float4*)(gp + 4));
    *(ushort8*)&Bu[0][bws] = pack_bf16x8(*(const float4*)up, *(const float4*)(up + 4));
  }
  __syncthreads();

  for (int t = 0; t < KT_A; ++t) {
    const int cur = t & 1, nxt = cur ^ 1;
    const int kn = (t + 1 < KT_A) ? (t + 1) * BK : 0;

    // 1) issue next-tile A directly to LDS[nxt]
    lds_cp16(xg + arow0 + kn, &Alds[nxt][tid * 8]);
    lds_cp16(xg + arow1 + kn, &Alds[nxt][(tid + 256) * 8]);
    // 2) issue next-tile B f32 loads into regs
    const float* gp = gbase + boff + kn;
    const float* up = ubase + boff + kn;
    const float4 g0 = *(const float4*)gp, g1 = *(const float4*)(gp + 4);
    const float4 u0 = *(const float4*)up, u1 = *(const float4*)(up + 4);

    // 3) compute current tile
    bf16x8 a[4], bgf[2], buf_[2];
    #pragma unroll
    for (int mi = 0; mi < 4; ++mi) {
      int row = wm * 64 + mi * 16 + llo;
      a[mi] = *(const bf16x8*)&Alds[cur][row * BK + SWZ(row, lhi) * 8];
    }
    #pragma unroll
    for (int ni = 0; ni < 2; ++ni) {
      int row = wn * 32 + ni * 16 + llo;
      bgf[ni] = *(const bf16x8*)&Bg[cur][row * BK + SWZ(row, lhi) * 8];
      buf_[ni] = *(const bf16x8*)&Bu[cur][row * BK + SWZ(row, lhi) * 8];
    }
    #pragma unroll
    for (int mi = 0; mi < 4; ++mi)
      #pragma unroll
      for (int ni = 0; ni < 2; ++ni) {
        accg[mi][ni] = __builtin_amdgcn_mfma_f32_16x16x32_bf16(a[mi], bgf[ni], accg[mi][ni], 0, 0, 0);
        accu[mi][ni] = __builtin_amdgcn_mfma_f32_16x16x32_bf16(a[mi], buf_[ni], accu[mi][ni], 0, 0, 0);
      }

    // 4) convert + write next-tile B into LDS[nxt]
    *(ushort8*)&Bg[nxt][bws] = pack_bf16x8(g0, g1);
    *(ushort8*)&Bu[nxt][bws] = pack_bf16x8(u0, u1);
    __syncthreads();
  }

  // epilogue: h = silu(g)*u*w -> bf16
  #pragma unroll
  for (int mi = 0; mi < 4; ++mi) {
    #pragma unroll
    for (int r = 0; r < 4; ++r) {
      int row = wm * 64 + mi * 16 + lhi * 4 + r;
      if (row < valid) {
        int grow = row_base + row;
        float wv = wgt[grow];
        size_t base = (size_t)grow * DFF + n0 + wn * 32;
        #pragma unroll
        for (int ni = 0; ni < 2; ++ni) {
          float g = accg[mi][ni][r];
          float u = accu[mi][ni][r];
          float h = (g / (1.f + __expf(-g))) * u * wv;
          hbuf[base + ni * 16 + llo] = f2bf(h);
        }
      }
    }
  }
}

// ---------- 4. grouped GEMM (split-K, 2-phase pipelined): y = h downT ----------
#define BM_B 128
#define BN_B 64
#define NT_B (D_DIM / BN_B)     // 16
#define MT_B (NROWS / BM_B)     // 32
#define NWG_B (NT_B * MT_B * NEXP * SPLITK)  // 8192
#define KT_B (KSLICE / BK)      // 44

template <bool USE_YBUF>
__global__ __launch_bounds__(256) void moe_down(
    const float* __restrict__ down_w,
    const unsigned short* __restrict__ hbuf,
    const int* __restrict__ tok,
    const int* __restrict__ cnt, const int* __restrict__ off,
    float* __restrict__ ybuf_or_out)
{
  const int orig = blockIdx.x;
  const int wgid = (orig & 7) * (NWG_B >> 3) + (orig >> 3);
  const int mt = wgid % MT_B;
  const int t1 = wgid / MT_B;
  const int nt = t1 % NT_B;
  const int t2 = t1 / NT_B;
  const int e  = t2 % NEXP;
  const int sl = t2 / NEXP;           // k-slice

  const int cnte = cnt[e];
  const int m0 = mt * BM_B;
  if (m0 >= cnte) return;
  const int row_base = off[e] + m0;
  const int valid = min(BM_B, cnte - m0);
  const int n0 = nt * BN_B;
  const int kbeg = sl * KSLICE;

  __shared__ __align__(16) unsigned short Alds[2][BM_B * BK]; // 2 x 8KB
  __shared__ __align__(16) unsigned short Blds[2][BN_B * BK]; // 2 x 4KB

  const int tid = threadIdx.x, lane = tid & 63, wid = tid >> 6;
  const int wm = wid >> 1, wn = wid & 1;   // wave subtile 64x32
  const int lhi = lane >> 4, llo = lane & 15;

  f32x4 acc[4][2];
  #pragma unroll
  for (int i = 0; i < 4; ++i)
    #pragma unroll
    for (int j = 0; j < 2; ++j) acc[i][j] = (f32x4){0.f, 0.f, 0.f, 0.f};

  const float* dbase = down_w + ((size_t)e * D_DIM + n0) * DFF;
  const int rowb = tid >> 2, gidx = tid & 3;
  const int ar0 = tid >> 2,          ag0 = tid & 3;
  const int ar1 = (tid + 256) >> 2,  ag1 = tid & 3;
  const size_t arow0 = (size_t)(row_base + min(ar0, valid - 1)) * DFF + SWZ(ar0, ag0) * 8;
  const size_t arow1 = (size_t)(row_base + min(ar1, valid - 1)) * DFF + SWZ(ar1, ag1) * 8;
  const size_t boff  = (size_t)rowb * DFF + gidx * 8;
  const int bws = rowb * BK + SWZ(rowb, gidx) * 8;

  // prologue: stage k=kbeg into buffer 0
  lds_cp16(hbuf + arow0 + kbeg, &Alds[0][tid * 8]);
  lds_cp16(hbuf + arow1 + kbeg, &Alds[0][(tid + 256) * 8]);
  {
    const float* dp = dbase + boff + kbeg;
    *(ushort8*)&Blds[0][bws] = pack_bf16x8(*(const float4*)dp, *(const float4*)(dp + 4));
  }
  __syncthreads();

  for (int t = 0; t < KT_B; ++t) {
    const int cur = t & 1, nxt = cur ^ 1;
    const int kn = kbeg + ((t + 1 < KT_B) ? (t + 1) * BK : 0);

    lds_cp16(hbuf + arow0 + kn, &Alds[nxt][tid * 8]);
    lds_cp16(hbuf + arow1 + kn, &Alds[nxt][(tid + 256) * 8]);
    const float* dp = dbase + boff + kn;
    const float4 d0 = *(const float4*)dp, d1 = *(const float4*)(dp + 4);

    bf16x8 a[4], b[2];
    #pragma unroll
    for (int mi = 0; mi < 4; ++mi) {
      int row = wm * 64 + mi * 16 + llo;
      a[mi] = *(const bf16x8*)&Alds[cur][row * BK + SWZ(row, lhi) * 8];
    }
    #pragma unroll
    for (int ni = 0; ni < 2; ++ni) {
      int row = wn * 32 + ni * 16 + llo;
      b[ni] = *(const bf16x8*)&Blds[cur][row * BK + SWZ(row, lhi) * 8];
    }
    #pragma unroll
    for (int mi = 0; mi < 4; ++mi)
      #pragma unroll
      for (int ni = 0; ni < 2; ++ni)
        acc[mi][ni] = __builtin_amdgcn_mfma_f32_16x16x32_bf16(a[mi], b[ni], acc[mi][ni], 0, 0, 0);

    *(ushort8*)&Blds[nxt][bws] = pack_bf16x8(d0, d1);
    __syncthreads();
  }

  #pragma unroll
  for (int mi = 0; mi < 4; ++mi) {
    #pragma unroll
    for (int r = 0; r < 4; ++r) {
      int row = wm * 64 + mi * 16 + lhi * 4 + r;
      if (row < valid) {
        if (USE_YBUF) {
          float* yp = ybuf_or_out + ((size_t)sl * NROWS + row_base + row) * D_DIM + n0 + wn * 32;
          #pragma unroll
          for (int ni = 0; ni < 2; ++ni) yp[ni * 16 + llo] = acc[mi][ni][r];
        } else {
          int tk = tok[row_base + row];
          float* op = ybuf_or_out + (size_t)tk * D_DIM + n0 + wn * 32;
          #pragma unroll
          for (int ni = 0; ni < 2; ++ni) atomicAdd(op + ni * 16 + llo, acc[mi][ni][r]);
        }
      }
    }
  }
}

// ---------- 5. combine: out[t] = sum over K slots and k-slices ----------
__global__ __launch_bounds__(256) void combine_kernel(
    const float* __restrict__ ybuf, const int* __restrict__ rowmap,
    float* __restrict__ out)
{
  const int t = blockIdx.x;
  const int d = threadIdx.x * 4;
  const int r0 = rowmap[t * 2], r1 = rowmap[t * 2 + 1];
  const float4 a0 = *(const float4*)(ybuf + ((size_t)r0) * D_DIM + d);
  const float4 a1 = *(const float4*)(ybuf + ((size_t)NROWS + r0) * D_DIM + d);
  const float4 b0 = *(const float4*)(ybuf + ((size_t)r1) * D_DIM + d);
  const float4 b1 = *(const float4*)(ybuf + ((size_t)NROWS + r1) * D_DIM + d);
  float4 s;
  s.x = (a0.x + a1.x) + (b0.x + b1.x);
  s.y = (a0.y + a1.y) + (b0.y + b1.y);
  s.z = (a0.z + a1.z) + (b0.z + b1.z);
  s.w = (a0.w + a1.w) + (b0.w + b1.w);
  *(float4*)(out + (size_t)t * D_DIM + d) = s;
}

// ---------- launch ----------
extern "C" void kernel_launch(void* const* d_in, const int* in_sizes, int n_in,
                              void* d_out, int out_size, void* d_ws, size_t ws_size,
                              hipStream_t stream) {
  const float* x      = (const float*)d_in[0];
  const float* topk_w = (const float*)d_in[1];
  const float* gate_w = (const float*)d_in[2];
  const float* up_w   = (const float*)d_in[3];
  const float* down_w = (const float*)d_in[4];
  const int*   ids    = (const int*)d_in[5];
  float* out = (float*)d_out;

  char* ws = (char*)d_ws;
  int*   cnt    = (int*)(ws + 0);
  int*   off    = (int*)(ws + 32);
  int*   tok    = (int*)(ws + 64);
  float* wgt    = (float*)(ws + 64 + NROWS * 4);
  int*   rowmap = (int*)(ws + 64 + NROWS * 8);
  unsigned short* xg   = (unsigned short*)(ws + 65536);
  unsigned short* hbuf = (unsigned short*)(ws + 65536 + (size_t)NROWS * D_DIM * 2);
  float* ybuf = (float*)(ws + 65536 + (size_t)NROWS * D_DIM * 2 + (size_t)NROWS * DFF * 2);
  const size_t needed = 65536 + (size_t)NROWS * D_DIM * 2 + (size_t)NROWS * DFF * 2
                      + (size_t)SPLITK * NROWS * D_DIM * 4;
  const bool use_ybuf = ws_size >= needed;

  routing_kernel<<<1, 512, 0, stream>>>(ids, topk_w, cnt, off, tok, wgt, rowmap);
  gather_x_kernel<<<NROWS, 256, 0, stream>>>(x, tok, xg);
  moe_gateup<<<NWG_A, 256, 0, stream>>>(gate_w, up_w, xg, wgt, cnt, off, hbuf);
  if (use_ybuf) {
    moe_down<true><<<NWG_B, 256, 0, stream>>>(down_w, hbuf, tok, cnt, off, ybuf);
    combine_kernel<<<T_TOK, 256, 0, stream>>>(ybuf, rowmap, out);
  } else {
    hipMemsetAsync(d_out, 0, (size_t)out_size * sizeof(float), stream);
    moe_down<false><<<NWG_B, 256, 0, stream>>>(down_w, hbuf, tok, cnt, off, out);
  }
}